// Round 1
// baseline (831.476 us; speedup 1.0000x reference)
//
#include <hip/hip_runtime.h>

#define V_   32000
#define D_   5120
#define T_   32
#define B_   4
#define S_   2048
#define VIS_ 768
#define NSH  (V_ + 2)        // 32002 shared rows (vocab + 2 figure tokens)

#define KSPLIT 4
#define KCHUNK (VIS_ / KSPLIT)   // 192

// ---------------------------------------------------------------------------
// Kernel 1: mark which (b, t) vision rows are actually referenced.
// Benign races: multiple threads store 1 to the same flag.
// ---------------------------------------------------------------------------
__global__ __launch_bounds__(256) void flag_k(const int* __restrict__ ids,
                                              int* __restrict__ flags) {
    int i = blockIdx.x * 256 + threadIdx.x;
    if (i >= B_ * S_) return;
    int id = ids[i];
    if (id >= NSH) {
        int t = id - NSH;
        if (t > T_ - 1) t = T_ - 1;           // matches jnp.clip upper bound
        int b = i / S_;
        flags[b * T_ + t] = 1;
    }
}

// ---------------------------------------------------------------------------
// Kernel 2: vx[row] = vision[row] @ fc_w + fc_b, only for flagged rows.
// grid = (D_/1024, B_*T_, KSPLIT), block = 256.
// Each thread owns 4 consecutive n (one float4 load of fc_w per k).
// K is split 4 ways for parallelism; partials combined with atomicAdd into
// the zero-initialized vx buffer. fc_b added by the z==0 block.
// ---------------------------------------------------------------------------
__global__ __launch_bounds__(256) void proj_k(const float* __restrict__ vision,
                                              const float* __restrict__ fc_w,
                                              const float* __restrict__ fc_b,
                                              const int* __restrict__ flags,
                                              float* __restrict__ vx) {
    int row = blockIdx.y;
    if (flags[row] == 0) return;

    __shared__ float vrow[KCHUNK];
    int k0 = blockIdx.z * KCHUNK;
    for (int k = threadIdx.x; k < KCHUNK; k += 256)
        vrow[k] = vision[(size_t)row * VIS_ + k0 + k];
    __syncthreads();

    int n = blockIdx.x * 1024 + threadIdx.x * 4;

    float4 acc;
    if (blockIdx.z == 0) {
        acc = *(const float4*)(fc_b + n);
    } else {
        acc.x = acc.y = acc.z = acc.w = 0.f;
    }

    const char* wbase = (const char*)(fc_w + (size_t)k0 * D_ + n);
    #pragma unroll 8
    for (int k = 0; k < KCHUNK; ++k) {
        float v = vrow[k];
        float4 w = *(const float4*)(wbase + (size_t)k * (D_ * sizeof(float)));
        acc.x += v * w.x;
        acc.y += v * w.y;
        acc.z += v * w.z;
        acc.w += v * w.w;
    }

    float* dst = vx + (size_t)row * D_ + n;
    atomicAdd(dst + 0, acc.x);
    atomicAdd(dst + 1, acc.y);
    atomicAdd(dst + 2, acc.z);
    atomicAdd(dst + 3, acc.w);
}

// ---------------------------------------------------------------------------
// Kernel 3: the gather. One block per (b, s) token; 256 threads stream the
// 5120-float row as 5 float4 per thread (fully coalesced 16B/lane).
// ---------------------------------------------------------------------------
__global__ __launch_bounds__(256) void gather_k(const int* __restrict__ ids,
                                                const float* __restrict__ weight,
                                                const float* __restrict__ fig,
                                                const float* __restrict__ vx,
                                                float* __restrict__ out) {
    int bs = blockIdx.x;
    int id = ids[bs];

    const float* src;
    if (id < V_) {
        src = weight + (size_t)id * D_;
    } else if (id < NSH) {
        src = fig + (size_t)(id - V_) * D_;
    } else {
        int t = id - NSH;
        if (t > T_ - 1) t = T_ - 1;
        int b = bs / S_;
        src = vx + (size_t)(b * T_ + t) * D_;
    }

    const float4* s4 = (const float4*)src;
    float4*       d4 = (float4*)(out + (size_t)bs * D_);
    int tid = threadIdx.x;
    #pragma unroll
    for (int i = 0; i < D_ / 4 / 256; ++i) {      // 5 iterations
        d4[tid + 256 * i] = s4[tid + 256 * i];
    }
}

// ---------------------------------------------------------------------------
extern "C" void kernel_launch(void* const* d_in, const int* in_sizes, int n_in,
                              void* d_out, int out_size, void* d_ws, size_t ws_size,
                              hipStream_t stream) {
    const int*   ids    = (const int*)d_in[0];      // [B, S]
    const float* vision = (const float*)d_in[1];    // [B, T, VIS]
    const float* weight = (const float*)d_in[2];    // [V, D]
    const float* fig    = (const float*)d_in[3];    // [2, D]
    const float* fc_w   = (const float*)d_in[4];    // [VIS, D]
    const float* fc_b   = (const float*)d_in[5];    // [D]
    float*       out    = (float*)d_out;            // [B, S, D]

    const size_t vx_bytes = (size_t)B_ * T_ * D_ * sizeof(float);   // 2.62 MB
    float* vx    = (float*)d_ws;
    int*   flags = (int*)((char*)d_ws + vx_bytes);

    // zero vx (atomic accumulation target) and flags in one memset
    hipMemsetAsync(d_ws, 0, vx_bytes + (size_t)B_ * T_ * sizeof(int), stream);

    flag_k<<<(B_ * S_ + 255) / 256, 256, 0, stream>>>(ids, flags);

    dim3 pg(D_ / 1024, B_ * T_, KSPLIT);
    proj_k<<<pg, 256, 0, stream>>>(vision, fc_w, fc_b, flags, vx);

    gather_k<<<B_ * S_, 256, 0, stream>>>(ids, weight, fig, vx, out);
}